// Round 6
// baseline (203.838 us; speedup 1.0000x reference)
//
#include <hip/hip_runtime.h>

typedef __bf16 bf16x8 __attribute__((ext_vector_type(8)));
typedef __bf16 bf16x4 __attribute__((ext_vector_type(4)));
typedef float  f32x4  __attribute__((ext_vector_type(4)));

__device__ __forceinline__ void g2l16(const void* g, void* l) {
    __builtin_amdgcn_global_load_lds((const __attribute__((address_space(1))) void*)g,
                                     (__attribute__((address_space(3))) void*)l, 16, 0, 0);
}

// Shared NT K-loop core. Tile = (MCH*32) x (NCH*32), 4 waves in 2x2,
// wave tile = MCH*16 x NCH*16. BK=64.
// LDS: unpadded [rows][64] bf16, 16B-unit XOR swizzle (unit ^= row&7) applied
// at the global SOURCE column during global_load_lds staging and at fragment
// reads -> 0 bank conflicts (verified R2/R4/R5).
// At/Bt point at the TILE origin (base + tile_row*ld).
template<int MCH, int NCH>
__device__ __forceinline__ void gemm_core(
    const __bf16* __restrict__ At, const __bf16* __restrict__ Bt,
    int lda, int ldb, int K,
    __bf16* As, __bf16* Bs, f32x4 (&acc)[MCH][NCH], int tid)
{
    const int w = tid >> 6, lane = tid & 63;
    const int quad = lane >> 4, l16 = lane & 15;
    const int wm = w & 1, wn = w >> 1;

    const int srow = (w << 3) + (lane >> 3);
    const int scol = ((lane & 7) ^ (lane >> 3)) << 3;
    char* ldsA = (char*)As + (size_t)w * 1024;
    char* ldsB = (char*)Bs + (size_t)w * 1024;
    const __bf16* Ag = At + (size_t)srow * lda + scol;
    const __bf16* Bg = Bt + (size_t)srow * ldb + scol;

    for (int k0 = 0; k0 < K; k0 += 64) {
        __syncthreads();
        #pragma unroll
        for (int c = 0; c < MCH; c++)
            g2l16(Ag + (size_t)(c * 32) * lda + k0, ldsA + c * 4096);
        #pragma unroll
        for (int c = 0; c < NCH; c++)
            g2l16(Bg + (size_t)(c * 32) * ldb + k0, ldsB + c * 4096);
        __syncthreads();

        #pragma unroll
        for (int kk = 0; kk < 64; kk += 32) {
            const int ub = kk >> 3;
            bf16x8 a[MCH], b[NCH];
            #pragma unroll
            for (int mt = 0; mt < MCH; mt++) {
                const int row = wm * (MCH * 16) + mt * 16 + l16;
                a[mt] = *(const bf16x8*)&As[row * 64 + (((quad + ub) ^ (row & 7)) << 3)];
            }
            #pragma unroll
            for (int nt = 0; nt < NCH; nt++) {
                const int row = wn * (NCH * 16) + nt * 16 + l16;
                b[nt] = *(const bf16x8*)&Bs[row * 64 + (((quad + ub) ^ (row & 7)) << 3)];
            }
            #pragma unroll
            for (int mt = 0; mt < MCH; mt++)
                #pragma unroll
                for (int nt = 0; nt < NCH; nt++)
                    acc[mt][nt] = __builtin_amdgcn_mfma_f32_16x16x32_bf16(
                        a[mt], b[nt], acc[mt][nt], 0, 0, 0);
        }
    }
}

// All GEMMs store C^T (addr j*ldc + i): a lane's 4 acc elements are 4
// consecutive i (A-rows) -> contiguous -> bf16x4/f32x4 vector stores.

// Projections, flat grid 1536. z = id/512 picks q/k/v.
// z<2: A=W_z (i=o), B=x (j=xrow) -> C^T = q/k[xrow][o], bf16x4 stores.
// z==2: A=x (i=xrow), B=Wv (j=d) -> C^T = vT[d][xrow] ([256][32768]).
__global__ __launch_bounds__(256)
void gemm_proj(const __bf16* __restrict__ xb, const __bf16* __restrict__ Wb,
               const float* __restrict__ bpack, __bf16* __restrict__ qkv,
               __bf16* __restrict__ vT)
{
    __shared__ __align__(16) __bf16 As[128 * 64];
    __shared__ __align__(16) __bf16 Bs[128 * 64];
    const int tid = threadIdx.x;
    const int id  = blockIdx.x;
    const int z   = id >> 9;
    const int rr  = id & 511;

    const __bf16 *At, *Bt;
    int m0, n0;
    if (z < 2) {
        m0 = (rr & 1) * 128; n0 = (rr >> 1) * 128;
        At = Wb + z * 131072 + m0 * 256;
        Bt = xb + (size_t)n0 * 256;
    } else {
        m0 = (rr >> 1) * 128; n0 = (rr & 1) * 128;
        At = xb + (size_t)m0 * 256;
        Bt = Wb + 2 * 131072 + n0 * 256;
    }

    f32x4 acc[4][4] = {};
    gemm_core<4, 4>(At, Bt, 256, 256, 256, As, Bs, acc, tid);

    const int w = tid >> 6, lane = tid & 63, quad = lane >> 4, l16 = lane & 15;
    const int wm = w & 1, wn = w >> 1;
    #pragma unroll
    for (int mt = 0; mt < 4; mt++) {
        const int i0 = m0 + wm * 64 + mt * 16 + quad * 4;
        #pragma unroll
        for (int nt = 0; nt < 4; nt++) {
            const int j = n0 + wn * 64 + nt * 16 + l16;
            bf16x4 pk;
            if (z < 2) {
                const f32x4 bn = *(const f32x4*)&bpack[z * 256 + i0];
                #pragma unroll
                for (int r = 0; r < 4; r++) pk[r] = (__bf16)(acc[mt][nt][r] + bn[r]);
                *(bf16x4*)(qkv + (size_t)z * 8388608 + (size_t)j * 256 + i0) = pk;
            } else {
                const float bn = bpack[512 + j];
                #pragma unroll
                for (int r = 0; r < 4; r++) pk[r] = (__bf16)(acc[mt][nt][r] + bn);
                *(bf16x4*)(vT + (size_t)j * 32768 + i0) = pk;
            }
        }
    }
}

// Logits: A=k (i=m), B=q (j=n) -> C^T = E[n][m], exp + bf16x4 stores.
// XCD-sequential flat grid (R5-verified: FETCH 74->12.5MB): x=id%8 is the
// XCD slot; 64 consecutive s per batch -> q+k working set ~4MB = one L2.
__global__ __launch_bounds__(256)
void gemm_logits(const __bf16* __restrict__ qb, const __bf16* __restrict__ kb,
                 __bf16* __restrict__ E)
{
    __shared__ __align__(16) __bf16 As[128 * 64];
    __shared__ __align__(16) __bf16 Bs[128 * 64];
    const int tid = threadIdx.x;
    const int id  = blockIdx.x;
    const int x = id & 7, s = id >> 3;
    const int z = x + ((s >> 6) << 3);
    const int t = s & 63;
    const int m0 = (t & 7) * 128;      // m (k-row) tile
    const int n0 = (t >> 3) * 128;     // n (q-row) tile

    const __bf16* At = kb + (size_t)z * 262144 + m0 * 256;
    const __bf16* Bt = qb + (size_t)z * 262144 + n0 * 256;

    f32x4 acc[4][4] = {};
    gemm_core<4, 4>(At, Bt, 256, 256, 256, As, Bs, acc, tid);

    const int w = tid >> 6, lane = tid & 63, quad = lane >> 4, l16 = lane & 15;
    const int wm = w & 1, wn = w >> 1;
    __bf16* Eb = E + (size_t)z * 1048576;
    #pragma unroll
    for (int mt = 0; mt < 4; mt++) {
        const int i0 = m0 + wm * 64 + mt * 16 + quad * 4;
        #pragma unroll
        for (int nt = 0; nt < 4; nt++) {
            const int j = n0 + wn * 64 + nt * 16 + l16;
            bf16x4 pk;
            #pragma unroll
            for (int r = 0; r < 4; r++) pk[r] = (__bf16)__expf(acc[mt][nt][r]);
            *(bf16x4*)(Eb + (size_t)j * 1024 + i0) = pk;
        }
    }
}

// PV: A=vT (i=d, lda=32768), B=E[z] (j=n) -> C^T = out[n][d], f32x4 stores.
// 64x128 tile -> grid 1024 = 4 blocks/CU. XCD-sequential swizzle.
__global__ __launch_bounds__(256)
void gemm_pv(const __bf16* __restrict__ vT, const __bf16* __restrict__ E,
             float* __restrict__ out)
{
    __shared__ __align__(16) __bf16 As[64 * 64];    //  8 KB
    __shared__ __align__(16) __bf16 Bs[128 * 64];   // 16 KB
    const int tid = threadIdx.x;
    const int id  = blockIdx.x;
    const int x = id & 7, s = id >> 3;               // s: 0..127
    const int z = x + ((s >> 5) << 3);
    const int t = s & 31;
    const int m0 = (t & 3) * 64;        // d tile
    const int n0 = (t >> 2) * 128;      // n tile

    const __bf16* At = vT + (size_t)m0 * 32768 + z * 1024;
    const __bf16* Bt = E + (size_t)z * 1048576 + (size_t)n0 * 1024;

    f32x4 acc[2][4] = {};
    gemm_core<2, 4>(At, Bt, 32768, 1024, 1024, As, Bs, acc, tid);

    const int w = tid >> 6, lane = tid & 63, quad = lane >> 4, l16 = lane & 15;
    const int wm = w & 1, wn = w >> 1;
    float* Ob = out + (size_t)z * 262144;
    #pragma unroll
    for (int mt = 0; mt < 2; mt++) {
        const int i0 = m0 + wm * 32 + mt * 16 + quad * 4;
        #pragma unroll
        for (int nt = 0; nt < 4; nt++) {
            const int j = n0 + wn * 64 + nt * 16 + l16;
            *(f32x4*)(Ob + (size_t)j * 256 + i0) = acc[mt][nt];
        }
    }
}

// One launch: x -> bf16, Wq/Wk/Wv -> bf16, pack 3 fp32 biases.
__global__ __launch_bounds__(256)
void cvt_all(const float* __restrict__ x,
             const float* __restrict__ Wq, const float* __restrict__ Wk,
             const float* __restrict__ Wv,
             const float* __restrict__ bq, const float* __restrict__ bk,
             const float* __restrict__ bv,
             __bf16* __restrict__ xb, __bf16* __restrict__ Wqb,
             float* __restrict__ bpack)
{
    const int i = blockIdx.x * 256 + threadIdx.x;
    if (i < 1073152) {
        const float* s; __bf16* d; int off;
        if (i < 1048576)      { s = x;  d = xb;            off = i; }
        else if (i < 1056768) { s = Wq; d = Wqb;           off = i - 1048576; }
        else if (i < 1064960) { s = Wk; d = Wqb + 131072;  off = i - 1056768; }
        else                  { s = Wv; d = Wqb + 262144;  off = i - 1064960; }
        const float4* s4 = (const float4*)s;
        const float4 f0 = s4[off * 2], f1 = s4[off * 2 + 1];
        bf16x8 o;
        o[0] = (__bf16)f0.x; o[1] = (__bf16)f0.y; o[2] = (__bf16)f0.z; o[3] = (__bf16)f0.w;
        o[4] = (__bf16)f1.x; o[5] = (__bf16)f1.y; o[6] = (__bf16)f1.z; o[7] = (__bf16)f1.w;
        ((bf16x8*)d)[off] = o;
    } else if (i < 1073344) {
        const int j = i - 1073152;
        const int sel = j >> 6, jj = j & 63;
        const float* s = sel == 0 ? bq : (sel == 1 ? bk : bv);
        ((float4*)bpack)[j] = ((const float4*)s)[jj];
    }
}

// Batch-axis softmax: S = sum_b E[b,:,:]; E <- E/S. Single pass, 32 slices
// cached in registers.
__global__ __launch_bounds__(256)
void softmax_norm(__bf16* __restrict__ E)
{
    const size_t p = (size_t)blockIdx.x * 256 + threadIdx.x;
    bf16x8* E8 = (bf16x8*)E;
    bf16x8 e[32];
    #pragma unroll
    for (int b = 0; b < 32; b++) e[b] = E8[(size_t)b * 131072 + p];
    float s[8] = {0.f, 0.f, 0.f, 0.f, 0.f, 0.f, 0.f, 0.f};
    #pragma unroll
    for (int b = 0; b < 32; b++)
        #pragma unroll
        for (int j = 0; j < 8; j++) s[j] += (float)e[b][j];
    float rs[8];
    #pragma unroll
    for (int j = 0; j < 8; j++) rs[j] = __builtin_amdgcn_rcpf(s[j]);
    #pragma unroll
    for (int b = 0; b < 32; b++) {
        bf16x8 o = e[b];
        #pragma unroll
        for (int j = 0; j < 8; j++) o[j] = (__bf16)((float)o[j] * rs[j]);
        E8[(size_t)b * 131072 + p] = o;
    }
}

extern "C" void kernel_launch(void* const* d_in, const int* in_sizes, int n_in,
                              void* d_out, int out_size, void* d_ws, size_t ws_size,
                              hipStream_t stream)
{
    const float* x  = (const float*)d_in[0];
    const float* Wq = (const float*)d_in[1];
    const float* bq = (const float*)d_in[2];
    const float* Wk = (const float*)d_in[3];
    const float* bk = (const float*)d_in[4];
    const float* Wv = (const float*)d_in[5];
    const float* bv = (const float*)d_in[6];
    float* out = (float*)d_out;

    // Workspace layout (bytes):
    //   [0,16M)    xb   bf16 (32768x256)
    //   [16M,32M)  qb  bf16 [32768][256] \
    //   [32M,48M)  kb  bf16 [32768][256]  } stride 16M (8388608 elem)
    //   [48M,64M)  vT  bf16 [256][32768]
    //   [64M,128M) E   bf16 (32,1024,1024)
    //   [128M,+768K) Wqb/Wkb/Wvb bf16 contiguous
    //   [+768K,+771K) bpack fp32[768]
    char* ws = (char*)d_ws;
    __bf16* xb    = (__bf16*)(ws);
    __bf16* qkv   = (__bf16*)(ws + (16u << 20));
    __bf16* vT    = (__bf16*)(ws + (48u << 20));
    __bf16* E     = (__bf16*)(ws + (64u << 20));
    __bf16* Wqb   = (__bf16*)(ws + (128u << 20));
    float*  bpack = (float*) (ws + (128u << 20) + (3u << 18));

    // 1) converts + bias pack
    cvt_all<<<4194, 256, 0, stream>>>(x, Wq, Wk, Wv, bq, bk, bv, xb, Wqb, bpack);

    // 2) q/k/v projections (C^T stores)
    gemm_proj<<<1536, 256, 0, stream>>>(xb, Wqb, bpack, qkv, vT);

    // 3) E[b][n][m] = exp(q[n].k[m]) (A=k, B=q -> C^T = E, vector stores)
    gemm_logits<<<2048, 256, 0, stream>>>(qkv, qkv + 8388608, E);

    // 4) batch-axis softmax normalize in place
    softmax_norm<<<512, 256, 0, stream>>>(E);

    // 5) out[b][n][d] (A=vT, B=E -> C^T = out, f32x4 stores)
    gemm_pv<<<1024, 256, 0, stream>>>(vT, E, out);
}